// Round 4
// baseline (421.777 us; speedup 1.0000x reference)
//
#include <hip/hip_runtime.h>

typedef unsigned short ushort_t;
typedef unsigned int uint_t;
typedef __attribute__((ext_vector_type(8))) _Float16 f16x8;
typedef __attribute__((ext_vector_type(4))) float floatx4;

#define ZDIM 32
#define KDIM 4
#define HDIM 128
#define B_TOTAL 32768
#define TB 16

// ws layout (ushort element offsets): Wd fp16 [k][n][c], Wsm fp16 [m][n][c]
#define WS_WD16 0            // 4*1024*128 = 524288
#define WS_SM16 524288       // 3*128*128 = 49152

// LDS layout. Round-16 change: producer-consumer pipeline. TB=16 so TWO
// D buffers fit: GEMM waves (4-7) write D(k+1) while flow waves (0-3)
// consume D(k). D fp16 [i][j][b16+2pad]: PJ=18 halves (36 B -> b32-aligned
// writes), PI=32*18+4=580 halves (290 words == 2 mod 32: dz row-reads
// 2-way thanks to +fg parity; pre col-reads 2-way via 9-coprime-32).
#define D_PI 580             // halves
#define D_PJ 18              // halves
#define D_BUFH 18560         // halves per buffer (32*580); 37120 B
#define SH_D_OFF 0           // 2 bufs = 74240 B
#define AUX_PITCH 132
#define AUX_MS (16 * AUX_PITCH)
#define SH_AUX_OFF 0         // float [3][16][132] = 25344 B (transient, aliases D)
#define SH_H_OFF 25344       // half [16][136] = 4352 B (transient; ends 29696)
#define SH_ZT_OFF 74240      // float z^T [i][18] = 2304 B
#define SH_TT_OFF 76544      // half t^T [j][18] = 1152 B
#define LDS_BYTES 77696      // x2 = 155392 <= 163840 -> 2 WGs/CU

__device__ __forceinline__ float fast_tanh(float x) {
    float e = __expf(2.0f * x);
    return 1.0f - 2.0f / (e + 1.0f);
}
__device__ __forceinline__ float f16lo(uint_t v) {
    return (float)__builtin_bit_cast(_Float16, (ushort_t)(v & 0xFFFFu));
}
__device__ __forceinline__ float f16hi(uint_t v) {
    return (float)__builtin_bit_cast(_Float16, (ushort_t)(v >> 16));
}
__device__ __forceinline__ ushort_t f2h(float x) {
    return __builtin_bit_cast(ushort_t, (_Float16)x);
}
__device__ __forceinline__ ushort4 cvt4(float4 v) {
    ushort4 o; o.x = f2h(v.x); o.y = f2h(v.y); o.z = f2h(v.z); o.w = f2h(v.w);
    return o;
}
__device__ __forceinline__ uint2 packq(const float* p) {
    uint2 r;
    r.x = (uint_t)f2h(p[0]) | ((uint_t)f2h(p[1]) << 16);
    r.y = (uint_t)f2h(p[2]) | ((uint_t)f2h(p[3]) << 16);
    return r;
}
// runtime-kk variant: 2 cndmasks, cheap (k-loop is rolled this round)
__device__ __forceinline__ float half_at(uint2 q, int kk) {
    uint_t w = (kk & 2) ? q.y : q.x;
    return (kk & 1) ? f16hi(w) : f16lo(w);
}

// ---------------------------------------------------------------------------
// Kernel 1: convert Wd (reordered per-k-slice) and Wd1/Wd2/Wb to fp16.
// ---------------------------------------------------------------------------
__global__ __launch_bounds__(256) void convert_kernel(
    const float* __restrict__ Wd, const float* __restrict__ Wd1,
    const float* __restrict__ Wd2, const float* __restrict__ Wb,
    ushort_t* __restrict__ ws)
{
    int g = blockIdx.x * 256 + threadIdx.x;
    if (g < 131072) {
        int k = g >> 15;            // 32768 float4 per k-slice
        int rem = g & 32767;
        int n = rem >> 5;           // n = i*32+j
        int c4 = rem & 31;
        float4 v = *((const float4*)Wd + (size_t)(4 * n + k) * 32 + c4);
        ((ushort4*)(ws + WS_WD16))[g] = cvt4(v);
    } else {
        int s = g - 131072;         // [0, 12288)
        const float* src = (s < 4096) ? Wd1 : ((s < 8192) ? Wd2 : Wb);
        int r = s & 4095;
        float4 v = ((const float4*)src)[r];
        ((ushort4*)(ws + WS_SM16))[s] = cvt4(v);
    }
}

// ---------------------------------------------------------------------------
// Kernel 2: pipelined producer-consumer. TB=16 batches/WG, 512 threads,
// 2 WGs/CU. Waves 4-7 = GEMM (produce D(k) into buf[k&1], 256 cols each);
// waves 0-3 = flow (consume D(k-1) from buf[(k-1)&1]). 5 pipeline steps,
// ONE barrier each. Every SIMD holds 2 GEMM + 2 flow waves (x2 WGs) at all
// times -> global-load latency, LDS latency and VALU co-schedule (m114),
// which the phase-locked r12-r15 structure could not do.
// ---------------------------------------------------------------------------
__global__ __launch_bounds__(512, 4) void sylv_kernel(
    const ushort_t* __restrict__ wsb,
    const float* __restrict__ hglob,
    const float* __restrict__ z0,
    const float* __restrict__ bd,
    const float* __restrict__ bd1,
    const float* __restrict__ bd2,
    const float* __restrict__ bb,
    float* __restrict__ out)
{
    extern __shared__ char smem[];
    _Float16* Dh     = (_Float16*)(smem + SH_D_OFF);
    float*    sh_aux = (float*)(smem + SH_AUX_OFF);
    _Float16* sh_h   = (_Float16*)(smem + SH_H_OFF);
    float*    sh_zt  = (float*)(smem + SH_ZT_OFF);
    _Float16* Th     = (_Float16*)(smem + SH_TT_OFF);

    const int t   = threadIdx.x;
    const int bg0 = blockIdx.x * TB;
    const int lane = t & 63, w = t >> 6;
    const int l15 = lane & 15, l4 = lane >> 4;
    // flow mapping (waves 0-3): fj = row/col index, fg = 2-batch group
    const int fj = t & 31;
    const int fg = (t >> 5) & 7;

    // ---- stage h (fp32 -> fp16, 512 float4) and z0 transposed ----
    {
        const float4* hsrc = (const float4*)(hglob + (size_t)bg0 * HDIM);
        float4 v = hsrc[t];                 // 16 rows x 32 float4 = 512
        int row = t >> 5, col4 = t & 31;
        *(ushort4*)((ushort_t*)sh_h + row * 136 + col4 * 4) = cvt4(v);
        if (t < 256) {
            int zb = t >> 4;                // 0..15 (batch)
            int zi0 = (t & 15) * 2;         // i index
            float2 zv = *(const float2*)(z0 + (size_t)(bg0 + zb) * ZDIM + zi0);
            sh_zt[zi0 * 18 + zb] = zv.x;
            sh_zt[(zi0 + 1) * 18 + zb] = zv.y;
        }
    }
    __syncthreads();

    // ---- GEMM waves: A fragments (16 rows) + small aux GEMMs ----
    f16x8 ah[4];
    if (w >= 4) {
        #pragma unroll
        for (int kc = 0; kc < 4; ++kc)
            ah[kc] = *(const f16x8*)(sh_h + l15 * 136 + kc * 32 + l4 * 8);
        // 24 (m,ntile) jobs over 4 GEMM waves
        #pragma unroll
        for (int pi = 0; pi < 6; ++pi) {
            int p = (w - 4) * 6 + pi;       // [0,24)
            int m_i = p >> 3, nt = p & 7, n = nt * 16 + l15;
            const _Float16* wp = (const _Float16*)(wsb + WS_SM16) + (size_t)(m_i * 128 + n) * 128 + l4 * 8;
            floatx4 a0 = {0.f, 0.f, 0.f, 0.f};
            #pragma unroll
            for (int kc = 0; kc < 4; ++kc) {
                f16x8 bh = *(const f16x8*)(wp + kc * 32);
                a0 = __builtin_amdgcn_mfma_f32_16x16x32_f16(ah[kc], bh, a0, 0, 0, 0);
            }
            const float* bv = (m_i == 0) ? bd1 : ((m_i == 1) ? bd2 : bb);
            float bias = bv[n];
            float* ap = sh_aux + m_i * AUX_MS + n;
            #pragma unroll
            for (int r = 0; r < 4; ++r) {
                float v0 = a0[r] + bias;
                if (m_i < 2) v0 = fast_tanh(v0);
                ap[(l4 * 4 + r) * AUX_PITCH] = v0;   // batches 0..15
            }
        }
    }
    __syncthreads();

    // ---- flow waves pack aux (2 batches x 4 k, fp16) into regs ----
    uint2 d1q[2], d2q[2], bpq[2];
    if (w < 4) {
        #pragma unroll
        for (int e = 0; e < 2; ++e) {
            const float* base = sh_aux + (2 * fg + e) * AUX_PITCH + 4 * fj;
            d1q[e] = packq(base);
            d2q[e] = packq(base + AUX_MS);
            bpq[e] = packq(base + 2 * AUX_MS);
        }
    }
    __syncthreads();    // pack done; D region (aliases aux/h) may be written

    float ldacc[2] = {0.f, 0.f};

    // ---- 5-step pipeline: step s runs GEMM(s) || flow(s-1), one barrier ----
    for (int s = 0; s < 5; ++s) {
        if (s < 4 && w >= 4) {
            const int kk = s;
            _Float16* buf = Dh + (s & 1) * D_BUFH;
            const _Float16* wdk = (const _Float16*)(wsb + WS_WD16) + (size_t)kk * 131072;
            #pragma unroll
            for (int g = 0; g < 16; ++g) {
                int nc = (w - 4) * 256 + g * 16 + l15;
                const _Float16* w0 = wdk + (size_t)nc * 128 + l4 * 8;
                floatx4 a0 = {0.f, 0.f, 0.f, 0.f};
                #pragma unroll
                for (int kc = 0; kc < 4; ++kc) {
                    f16x8 b0 = *(const f16x8*)(w0 + kc * 32);
                    a0 = __builtin_amdgcn_mfma_f32_16x16x32_f16(ah[kc], b0, a0, 0, 0, 0);
                }
                int ii = nc >> 5, jj = nc & 31;
                float bias0 = bd[4 * nc + kk];
                uint_t v0 = (uint_t)f2h(a0[0] + bias0) | ((uint_t)f2h(a0[1] + bias0) << 16);
                uint_t v1 = (uint_t)f2h(a0[2] + bias0) | ((uint_t)f2h(a0[3] + bias0) << 16);
                int off = ii * D_PI + jj * D_PJ + l4 * 4;    // halves
                *(uint_t*)(buf + off)     = v0;              // batches l4*4,+1
                *(uint_t*)(buf + off + 2) = v1;              // batches l4*4+2,+3
            }
        }
        if (s > 0 && w < 4) {
            const int kk = s - 1;
            const _Float16* buf = Dh + (kk & 1) * D_BUFH;
            const bool flip = (kk & 1) != 0;
            const int zr_j = flip ? (31 - fj) : fj;

            // ---- pre[j][b] = bp + z_per[j]*d2 + sum_{i>j} z_per[i]*D[i,j,b] ----
            float sa[2];
            {
                float2 zj = *(const float2*)(sh_zt + zr_j * 18 + 2 * fg);
                sa[0] = half_at(bpq[0], kk) + zj.x * half_at(d2q[0], kk);
                sa[1] = half_at(bpq[1], kk) + zj.y * half_at(d2q[1], kk);
            }
            #pragma unroll
            for (int i = 1; i < 32; ++i) {
                int zr_i = flip ? (31 - i) : i;
                float2 zi2 = *(const float2*)(sh_zt + zr_i * 18 + 2 * fg);  // broadcast
                uint_t dd = *(const uint_t*)(buf + i * D_PI + fj * D_PJ + 2 * fg);
                bool gt = (i > fj);
                sa[0] = fmaf(f16lo(dd), gt ? zi2.x : 0.f, sa[0]);
                sa[1] = fmaf(f16hi(dd), gt ? zi2.y : 0.f, sa[1]);
            }
            // ---- tanh, log-det, t -> LDS (fp16) ----
            float tq[2];
            tq[0] = fast_tanh(sa[0]);
            tq[1] = fast_tanh(sa[1]);
            {
                uint_t tv = (uint_t)f2h(tq[0]) | ((uint_t)f2h(tq[1]) << 16);
                *(uint_t*)(Th + fj * 18 + 2 * fg) = tv;
                #pragma unroll
                for (int e = 0; e < 2; ++e) {
                    float d1 = half_at(d1q[e], kk), d2 = half_at(d2q[e], kk);
                    ldacc[e] += __logf(fabsf((1.f - tq[e] * tq[e]) * (d1 * d2) + 1.f));
                }
            }
            // t producer (lane fj=j2) and consumer (lane fj=p) share the
            // wave (wave spans fj 0..31 x 2 fg): intra-wave handoff.
            asm volatile("s_waitcnt lgkmcnt(0)" ::: "memory");

            // ---- dz[p][b] = t[p]*d1 + sum_{j>p} t[j][b]*D[p,j,b] ----
            float dzv[2];
            dzv[0] = tq[0] * half_at(d1q[0], kk);
            dzv[1] = tq[1] * half_at(d1q[1], kk);
            #pragma unroll
            for (int j2 = 1; j2 < 32; ++j2) {
                uint_t tt2 = *(const uint_t*)(Th + j2 * 18 + 2 * fg);       // broadcast
                uint_t dd  = *(const uint_t*)(buf + fj * D_PI + j2 * D_PJ + 2 * fg);
                bool gt = (j2 > fj);
                dzv[0] = fmaf(f16lo(dd), gt ? f16lo(tt2) : 0.f, dzv[0]);
                dzv[1] = fmaf(f16hi(dd), gt ? f16hi(tt2) : 0.f, dzv[1]);
            }
            // ---- z[zr_j][b] += dz (each (zr_j, b-pair) has one owner) ----
            float* zp = sh_zt + zr_j * 18 + 2 * fg;
            float2 zc = *(float2*)zp;
            zc.x += dzv[0];
            zc.y += dzv[1];
            *(float2*)zp = zc;
        }
        __syncthreads();
    }

    // ---- epilogue: write z and log_det_j ----
    if (w < 4) {
        #pragma unroll
        for (int e = 0; e < 2; ++e)
            out[(size_t)(bg0 + 2 * fg + e) * ZDIM + fj] = sh_zt[fj * 18 + 2 * fg + e];
        #pragma unroll
        for (int e = 0; e < 2; ++e) {
            float v = ldacc[e];
            v += __shfl_xor(v, 1, 32);
            v += __shfl_xor(v, 2, 32);
            v += __shfl_xor(v, 4, 32);
            v += __shfl_xor(v, 8, 32);
            v += __shfl_xor(v, 16, 32);
            if (fj == 0) out[(size_t)B_TOTAL * ZDIM + bg0 + 2 * fg + e] = v;
        }
    }
}

extern "C" void kernel_launch(void* const* d_in, const int* in_sizes, int n_in,
                              void* d_out, int out_size, void* d_ws, size_t ws_size,
                              hipStream_t stream) {
    const float* z0  = (const float*)d_in[0];
    const float* h   = (const float*)d_in[1];
    const float* Wd  = (const float*)d_in[2];
    const float* bd  = (const float*)d_in[3];
    const float* Wd1 = (const float*)d_in[4];
    const float* bd1 = (const float*)d_in[5];
    const float* Wd2 = (const float*)d_in[6];
    const float* bd2 = (const float*)d_in[7];
    const float* Wb  = (const float*)d_in[8];
    const float* bb  = (const float*)d_in[9];
    ushort_t* ws = (ushort_t*)d_ws;
    float* out = (float*)d_out;

    convert_kernel<<<560, 256, 0, stream>>>(Wd, Wd1, Wd2, Wb, ws);

    (void)hipFuncSetAttribute((const void*)sylv_kernel,
                              hipFuncAttributeMaxDynamicSharedMemorySize, LDS_BYTES);
    sylv_kernel<<<B_TOTAL / TB, 512, LDS_BYTES, stream>>>(ws, h, z0, bd, bd1, bd2, bb, out);
}

// Round 5
// 244.881 us; speedup vs baseline: 1.7224x; 1.7224x over previous
//
#include <hip/hip_runtime.h>

typedef unsigned short ushort_t;
typedef unsigned int uint_t;
typedef __attribute__((ext_vector_type(8))) _Float16 f16x8;
typedef __attribute__((ext_vector_type(4))) _Float16 f16x4;
typedef __attribute__((ext_vector_type(4))) float floatx4;

#define ZDIM 32
#define KDIM 4
#define HDIM 128
#define B_TOTAL 32768
#define TB 32

// ws layout (ushort element offsets): Wd fp16 [k][n][c], Wsm fp16 [m][n][c]
#define WS_WD16 0            // 4*1024*128 = 524288
#define WS_SM16 524288       // 3*128*128 = 49152

// LDS layout (byte offsets). D stored [i][j][batch] (batch innermost, fp16):
// GEMM writes are ds_write_b64 (4 consecutive batches = the 4 MFMA acc rows),
// flow reads are b64/b128. Strides: D_BI/2=578==2 (mod 32), D_BJ/2=18.
// z fp32 transposed [i][b]; t fp16 [j][b].
#define D_BI 1156            // halves; i stride = 32*36+4
#define D_BJ 36              // halves; j stride = 32 batches + 4 pad
#define SH_D_OFF 0           // 32*1156*2 = 73984 B
#define AUX_PITCH 132
#define SH_AUX_OFF 0         // float [3][32][132] = 50688 B (pre-loop, aliases D)
#define SH_H_OFF 50688       // half [32][136] = 8704 B (pre-loop, aliases D; ends 59392)
#define SH_ZT_OFF 73984      // float z^T [i][36] = 4608 B (ends 78592)
#define SH_TT_OFF 78592      // half t^T [j][36] = 2304 B (ends 80896)
#define LDS_BYTES 80896      // x2 = 161792 <= 163840 -> 2 WGs/CU

__device__ __forceinline__ float fast_tanh(float x) {
    float e = __expf(2.0f * x);
    return 1.0f - 2.0f / (e + 1.0f);
}
__device__ __forceinline__ float f16lo(uint_t v) {
    return (float)__builtin_bit_cast(_Float16, (ushort_t)(v & 0xFFFFu));
}
__device__ __forceinline__ float f16hi(uint_t v) {
    return (float)__builtin_bit_cast(_Float16, (ushort_t)(v >> 16));
}
__device__ __forceinline__ ushort_t f2h(float x) {
    return __builtin_bit_cast(ushort_t, (_Float16)x);
}
__device__ __forceinline__ ushort4 cvt4(float4 v) {
    ushort4 o; o.x = f2h(v.x); o.y = f2h(v.y); o.z = f2h(v.z); o.w = f2h(v.w);
    return o;
}
// pack 4 floats into 2 dwords of fp16
__device__ __forceinline__ uint2 packq(const float* p) {
    uint2 r;
    r.x = (uint_t)f2h(p[0]) | ((uint_t)f2h(p[1]) << 16);
    r.y = (uint_t)f2h(p[2]) | ((uint_t)f2h(p[3]) << 16);
    return r;
}
// runtime-kk variant: kk is wave-uniform -> s_cselect + cndmask, cheap
__device__ __forceinline__ float half_at(uint2 q, int kk) {
    uint_t w = (kk & 2) ? q.y : q.x;
    return (kk & 1) ? f16hi(w) : f16lo(w);
}

// ---------------------------------------------------------------------------
// Kernel 1: convert Wd (reordered per-k-slice) and Wd1/Wd2/Wb to fp16.
// ---------------------------------------------------------------------------
__global__ __launch_bounds__(256) void convert_kernel(
    const float* __restrict__ Wd, const float* __restrict__ Wd1,
    const float* __restrict__ Wd2, const float* __restrict__ Wb,
    ushort_t* __restrict__ ws)
{
    int g = blockIdx.x * 256 + threadIdx.x;
    if (g < 131072) {
        int k = g >> 15;            // 32768 float4 per k-slice
        int rem = g & 32767;
        int n = rem >> 5;           // n = i*32+j
        int c4 = rem & 31;
        float4 v = *((const float4*)Wd + (size_t)(4 * n + k) * 32 + c4);
        ((ushort4*)(ws + WS_WD16))[g] = cvt4(v);
    } else {
        int s = g - 131072;         // [0, 12288)
        const float* src = (s < 4096) ? Wd1 : ((s < 8192) ? Wd2 : Wb);
        int r = s & 4095;
        float4 v = ((const float4*)src)[r];
        ((ushort4*)(ws + WS_SM16))[s] = cvt4(v);
    }
}

// ---------------------------------------------------------------------------
// Kernel 2: fused fp16 encoder GEMMs + K-step flow. TB=32 batches/WG,
// 512 threads (8 waves), 2 WGs/CU. Round-17 change vs round-1 kernel:
// ONLY loop rolling. Rounds 12-16 all fully unrolled k x 31-iter flow
// loops x 16-group GEMM (~40 KB body): register demand >> budget ->
// ~64 B/thread scratch spill (the 33 MB WRITE_SIZE excess = 512 thr x
// 1024 WG x 64 B), spill reloads from L2 on every inner-loop iteration —
// the structure-invariant 187 us wall. Rolled: k-loop unroll 1 (kk
// wave-uniform -> SALU selects), GEMM unroll 2, pre/dz unroll 4 over
// i,j2 = 0..31 (index 0 contributes 0 via the existing predicate).
// Body ~3 KB (I$-resident), live state fits 64 VGPRs.
// ---------------------------------------------------------------------------
__global__ __launch_bounds__(512, 4) void sylv_kernel(
    const ushort_t* __restrict__ wsb,
    const float* __restrict__ hglob,
    const float* __restrict__ z0,
    const float* __restrict__ bd,
    const float* __restrict__ bd1,
    const float* __restrict__ bd2,
    const float* __restrict__ bb,
    float* __restrict__ out)
{
    extern __shared__ char smem[];
    _Float16* Dh     = (_Float16*)(smem + SH_D_OFF);
    float*    sh_aux = (float*)(smem + SH_AUX_OFF);
    _Float16* sh_h   = (_Float16*)(smem + SH_H_OFF);
    float*    sh_zt  = (float*)(smem + SH_ZT_OFF);
    _Float16* Th     = (_Float16*)(smem + SH_TT_OFF);

    const int t   = threadIdx.x;
    const int bg0 = blockIdx.x * TB;
    const int lane = t & 63, w = t >> 6;    // w = 0..7 = column group
    const int l15 = lane & 15, l4 = lane >> 4;
    // flow mapping (t < 256): fj = column/row index, fg = batch group (4 b)
    const int fj = t & 31;
    const int fg = t >> 5;          // 0..7 for t<256

    // ---- stage h (fp32 -> fp16 in LDS) and z0 transposed ----
    {
        const float4* hsrc = (const float4*)(hglob + (size_t)bg0 * HDIM);
        #pragma unroll
        for (int it = 0; it < 2; ++it) {
            int c = t + it * 512;       // 1024 float4 chunks
            int row = c >> 5, col4 = c & 31;
            float4 v = hsrc[c];
            *(ushort4*)((ushort_t*)sh_h + row * 136 + col4 * 4) = cvt4(v);
        }
        int zb = t >> 4;                // 0..31 (batch)
        int zi0 = (t & 15) * 2;         // i index
        float2 zv = *(const float2*)(z0 + (size_t)(bg0 + zb) * ZDIM + zi0);
        sh_zt[zi0 * 36 + zb] = zv.x;
        sh_zt[(zi0 + 1) * 36 + zb] = zv.y;
    }
    __syncthreads();

    // ---- A fragments: TWO 16-row tiles (rows 0..31), same for all waves ----
    f16x8 ah[2][4];
    #pragma unroll
    for (int mt = 0; mt < 2; ++mt)
        #pragma unroll
        for (int kc = 0; kc < 4; ++kc)
            ah[mt][kc] = *(const f16x8*)(sh_h + (mt * 16 + l15) * 136 + kc * 32 + l4 * 8);

    // ---- small GEMMs (fp16): d1, d2, bpre -> aux[m][batch][n] ----
    #pragma unroll 1
    for (int pi = 0; pi < 3; ++pi) {
        int p = w * 3 + pi;             // [0,24)
        int m_i = p >> 3, nt = p & 7, n = nt * 16 + l15;
        const _Float16* wp = (const _Float16*)(wsb + WS_SM16) + (size_t)(m_i * 128 + n) * 128 + l4 * 8;
        floatx4 a0 = {0.f, 0.f, 0.f, 0.f}, a1 = {0.f, 0.f, 0.f, 0.f};
        #pragma unroll
        for (int kc = 0; kc < 4; ++kc) {
            f16x8 bh = *(const f16x8*)(wp + kc * 32);
            a0 = __builtin_amdgcn_mfma_f32_16x16x32_f16(ah[0][kc], bh, a0, 0, 0, 0);
            a1 = __builtin_amdgcn_mfma_f32_16x16x32_f16(ah[1][kc], bh, a1, 0, 0, 0);
        }
        const float* bv = (m_i == 0) ? bd1 : ((m_i == 1) ? bd2 : bb);
        float bias = bv[n];
        float* ap = sh_aux + m_i * (32 * AUX_PITCH) + n;
        #pragma unroll
        for (int r = 0; r < 4; ++r) {
            float v0 = a0[r] + bias, v1 = a1[r] + bias;
            if (m_i < 2) { v0 = fast_tanh(v0); v1 = fast_tanh(v1); }
            ap[(l4 * 4 + r) * AUX_PITCH] = v0;
            ap[(16 + l4 * 4 + r) * AUX_PITCH] = v1;
        }
    }
    __syncthreads();

    // ---- flow threads pack aux for (fj, 4 batches) x 4 k into fp16 regs ----
    uint2 d1q[4], d2q[4], bpq[4];
    if (t < 256) {
        #pragma unroll
        for (int e = 0; e < 4; ++e) {
            const float* base = sh_aux + (4 * fg + e) * AUX_PITCH + 4 * fj;
            d1q[e] = packq(base + 0 * (32 * AUX_PITCH));
            d2q[e] = packq(base + 1 * (32 * AUX_PITCH));
            bpq[e] = packq(base + 2 * (32 * AUX_PITCH));
        }
    }
    __syncthreads();

    float ld4[4] = {0.f, 0.f, 0.f, 0.f};

    #pragma unroll 1
    for (int kk = 0; kk < KDIM; ++kk) {
        // ---- GEMM: D_k[b][n] = h@Wd_k^T + bd; write [i][j][b] as b64 ----
        const _Float16* wdk = (const _Float16*)(wsb + WS_WD16) + (size_t)kk * 131072;
        #pragma unroll 2
        for (int g = 0; g < 8; ++g) {
            int nc = w * 128 + g * 16 + l15;
            const _Float16* w0 = wdk + (size_t)nc * 128 + l4 * 8;
            floatx4 a0 = {0.f,0.f,0.f,0.f}, a1 = {0.f,0.f,0.f,0.f};
            #pragma unroll
            for (int kc = 0; kc < 4; ++kc) {
                f16x8 b0 = *(const f16x8*)(w0 + kc * 32);
                a0 = __builtin_amdgcn_mfma_f32_16x16x32_f16(ah[0][kc], b0, a0, 0, 0, 0);
                a1 = __builtin_amdgcn_mfma_f32_16x16x32_f16(ah[1][kc], b0, a1, 0, 0, 0);
            }
            int ii = nc >> 5, jj = nc & 31;
            int base = ii * D_BI + jj * D_BJ;       // halves
            float bias0 = bd[4 * nc + kk];
            f16x4 o0, o1;
            #pragma unroll
            for (int r = 0; r < 4; ++r) {
                o0[r] = (_Float16)(a0[r] + bias0);
                o1[r] = (_Float16)(a1[r] + bias0);
            }
            *(f16x4*)(Dh + base + l4 * 4) = o0;           // batches l4*4..+3
            *(f16x4*)(Dh + base + 16 + l4 * 4) = o1;      // batches 16+l4*4..+3
        }
        __syncthreads();

        if (t < 256) {
            const bool flip = (kk & 1) != 0;
            const int zr_j = flip ? (31 - fj) : fj;

            // ---- pre[j][b] = bp + z_per[j]*d2 + sum_{i>j} z_per[i]*D[i,j,b] ----
            float s4[4];
            {
                floatx4 zj = *(const floatx4*)(sh_zt + zr_j * 36 + 4 * fg);
                #pragma unroll
                for (int e = 0; e < 4; ++e)
                    s4[e] = half_at(bpq[e], kk) + zj[e] * half_at(d2q[e], kk);
            }
            #pragma unroll 4
            for (int i = 0; i < 32; ++i) {      // i=0 contributes 0 (gt false)
                int zr_i = flip ? (31 - i) : i;
                floatx4 zi4 = *(const floatx4*)(sh_zt + zr_i * 36 + 4 * fg); // broadcast
                f16x4 dd = *(const f16x4*)(Dh + i * D_BI + fj * D_BJ + 4 * fg);
                bool gt = (i > fj);
                #pragma unroll
                for (int e = 0; e < 4; ++e)
                    s4[e] = fmaf((float)dd[e], gt ? zi4[e] : 0.0f, s4[e]);
            }
            // ---- tanh, log-det, t -> LDS (fp16) ----
            float tq4[4];
            {
                f16x4 tth;
                #pragma unroll
                for (int e = 0; e < 4; ++e) {
                    float tt = fast_tanh(s4[e]);
                    tq4[e] = tt;
                    tth[e] = (_Float16)tt;
                    float d1 = half_at(d1q[e], kk), d2 = half_at(d2q[e], kk);
                    ld4[e] += __logf(fabsf((1.f - tt * tt) * (d1 * d2) + 1.f));
                }
                *(f16x4*)(Th + fj * 36 + 4 * fg) = tth;
            }
            // t producer (lane j') and consumer (lane p) share the 32-lane
            // group: intra-wave handoff; wait + memory clobber pins ordering.
            asm volatile("s_waitcnt lgkmcnt(0)" ::: "memory");

            // ---- dz[p][b] = t[p]*d1 + sum_{j>p} t[j][b]*D[p,j,b] ----
            float dzv4[4];
            #pragma unroll
            for (int e = 0; e < 4; ++e)
                dzv4[e] = tq4[e] * half_at(d1q[e], kk);
            #pragma unroll 4
            for (int j2 = 0; j2 < 32; ++j2) {   // j2=0 contributes 0 (gt false)
                f16x4 tt4 = *(const f16x4*)(Th + j2 * 36 + 4 * fg);       // broadcast
                f16x4 dd  = *(const f16x4*)(Dh + fj * D_BI + j2 * D_BJ + 4 * fg);
                bool gt = (j2 > fj);
                #pragma unroll
                for (int e = 0; e < 4; ++e)
                    dzv4[e] = fmaf((float)dd[e], gt ? (float)tt4[e] : 0.0f, dzv4[e]);
            }
            // ---- z[b][zr_j] += dz ----
            float* zp = sh_zt + zr_j * 36 + 4 * fg;
            floatx4 zc = *(floatx4*)zp;
            #pragma unroll
            for (int e = 0; e < 4; ++e) zc[e] += dzv4[e];
            *(floatx4*)zp = zc;
        }
        __syncthreads();
    }

    // ---- epilogue: write z and log_det_j ----
    if (t < 256) {
        floatx4 zf = *(const floatx4*)(sh_zt + fj * 36 + 4 * fg);
        #pragma unroll
        for (int e = 0; e < 4; ++e)
            out[(size_t)(bg0 + 4 * fg + e) * ZDIM + fj] = zf[e];
        #pragma unroll
        for (int e = 0; e < 4; ++e) {
            float v = ld4[e];
            v += __shfl_xor(v, 1, 32);
            v += __shfl_xor(v, 2, 32);
            v += __shfl_xor(v, 4, 32);
            v += __shfl_xor(v, 8, 32);
            v += __shfl_xor(v, 16, 32);
            if (fj == 0) out[(size_t)B_TOTAL * ZDIM + bg0 + 4 * fg + e] = v;
        }
    }
}

extern "C" void kernel_launch(void* const* d_in, const int* in_sizes, int n_in,
                              void* d_out, int out_size, void* d_ws, size_t ws_size,
                              hipStream_t stream) {
    const float* z0  = (const float*)d_in[0];
    const float* h   = (const float*)d_in[1];
    const float* Wd  = (const float*)d_in[2];
    const float* bd  = (const float*)d_in[3];
    const float* Wd1 = (const float*)d_in[4];
    const float* bd1 = (const float*)d_in[5];
    const float* Wd2 = (const float*)d_in[6];
    const float* bd2 = (const float*)d_in[7];
    const float* Wb  = (const float*)d_in[8];
    const float* bb  = (const float*)d_in[9];
    ushort_t* ws = (ushort_t*)d_ws;
    float* out = (float*)d_out;

    convert_kernel<<<560, 256, 0, stream>>>(Wd, Wd1, Wd2, Wb, ws);

    (void)hipFuncSetAttribute((const void*)sylv_kernel,
                              hipFuncAttributeMaxDynamicSharedMemorySize, LDS_BYTES);
    sylv_kernel<<<B_TOTAL / TB, 512, LDS_BYTES, stream>>>(ws, h, z0, bd, bd1, bd2, bb, out);
}